// Round 5
// baseline (12774.328 us; speedup 1.0000x reference)
//
#include <hip/hip_runtime.h>
#include <stdint.h>

#define T_SEQ 1024
#define BATCH 32
#define HID   512
#define RING  32     // inter-stage ring depth (power of 2)

typedef unsigned short u16;
typedef unsigned long long u64;
typedef short bf16x8 __attribute__((ext_vector_type(8)));
typedef float f32x4  __attribute__((ext_vector_type(4)));

__device__ __forceinline__ float bf2f(u16 u) {
  union { unsigned u; float f; } v; v.u = ((unsigned)u) << 16; return v.f;
}
__device__ __forceinline__ u16 f2bf(float f) {
  union { float f; unsigned u; } v; v.f = f;
  unsigned r = v.u + 0x7fffu + ((v.u >> 16) & 1u);   // RNE
  return (u16)(r >> 16);
}
__device__ __forceinline__ float sigf(float x) { return 1.0f / (1.0f + __expf(-x)); }
__device__ __forceinline__ float tanh_fast(float x) { return 2.0f * sigf(2.0f * x) - 1.0f; }

// Device-scope coherent 8B load/store: bypass stale per-XCD L2, no wbl2/inv.
__device__ __forceinline__ u64 ld_dev(const u64* p) {
  return __hip_atomic_load(p, __ATOMIC_RELAXED, __HIP_MEMORY_SCOPE_AGENT);
}
__device__ __forceinline__ void st_dev(u64* p, u64 v) {
  __hip_atomic_store(p, v, __ATOMIC_RELAXED, __HIP_MEMORY_SCOPE_AGENT);
}
__device__ __forceinline__ int ld_flag(const int* p) {
  return __hip_atomic_load(p, __ATOMIC_RELAXED, __HIP_MEMORY_SCOPE_AGENT);
}

// ---------------- cast fp32 -> bf16 ----------------
__global__ __launch_bounds__(256) void cast_f32_bf16(const float* __restrict__ in,
                                                     u16* __restrict__ out, int n) {
  int i = (blockIdx.x * 256 + threadIdx.x) * 8;
  if (i + 7 < n) {
    float4 v0 = *reinterpret_cast<const float4*>(in + i);
    float4 v1 = *reinterpret_cast<const float4*>(in + i + 4);
    uint4 o;
    o.x = (unsigned)f2bf(v0.x) | ((unsigned)f2bf(v0.y) << 16);
    o.y = (unsigned)f2bf(v0.z) | ((unsigned)f2bf(v0.w) << 16);
    o.z = (unsigned)f2bf(v1.x) | ((unsigned)f2bf(v1.y) << 16);
    o.w = (unsigned)f2bf(v1.z) | ((unsigned)f2bf(v1.w) << 16);
    *reinterpret_cast<uint4*>(out + i) = o;
  } else {
    for (; i < n; ++i) out[i] = f2bf(in[i]);
  }
}

// ---------------- prep: W' = bf16(W ∘ g), Gn = Σ g*W, Bn = Σ b*W ----------------
// one wave per row of W [N x 512]
__global__ __launch_bounds__(256) void prep_wih(
    const float* __restrict__ w, const float* __restrict__ g, const float* __restrict__ b,
    u16* __restrict__ wout, float* __restrict__ Gn, float* __restrict__ Bn, int N)
{
  int row  = blockIdx.x * 4 + (threadIdx.x >> 6);
  int lane = threadIdx.x & 63;
  if (row >= N) return;
  const float* wr = w + (long)row * 512 + lane * 8;
  float sg = 0.f, sb = 0.f;
  u16 o[8];
#pragma unroll
  for (int i = 0; i < 8; ++i) {
    float wv = wr[i];
    float gv = g[lane * 8 + i];
    float bv = b[lane * 8 + i];
    o[i] = f2bf(wv * gv);
    sg += wv * gv;
    sb += wv * bv;
  }
  *reinterpret_cast<uint4*>(wout + (long)row * 512 + lane * 8) = *reinterpret_cast<uint4*>(o);
#pragma unroll
  for (int off = 1; off < 64; off <<= 1) { sg += __shfl_xor(sg, off); sb += __shfl_xor(sb, off); }
  if (lane == 0) { Gn[row] = sg; Bn[row] = sb; }
}

// ---------------- LSTM input GEMM: out[t][b][k][g] = x @ w_ih^T + b_ih + b_hh ----------------
__global__ __launch_bounds__(256) void gemm_xg(
    const u16* __restrict__ A, const u16* __restrict__ W,
    const float* __restrict__ bias1, const float* __restrict__ bias2,
    u16* __restrict__ out, int N, int K, int strideB, int strideT)
{
  __shared__ u16 As[64][72];
  __shared__ u16 Bs[64][72];
  int tid  = threadIdx.x;
  int lane = tid & 63;
  int wave = tid >> 6;
  int m0 = blockIdx.x * 64;
  int n0 = blockIdx.y * 64;

  f32x4 zero = {0.f, 0.f, 0.f, 0.f};
  f32x4 acc[4] = {zero, zero, zero, zero};

  int srow = tid >> 2;
  int scol = (tid & 3) * 16;

  int m_s = m0 + srow;
  long arow = (long)(m_s & (BATCH - 1)) * strideB + (long)(m_s >> 5) * strideT;
  const u16* aptr = A + arow * K + scol;
  const u16* wptr = W + (long)(n0 + srow) * K + scol;

  for (int kk = 0; kk < K; kk += 64) {
    __syncthreads();
    uint4 a0 = *reinterpret_cast<const uint4*>(aptr + kk);
    uint4 a1 = *reinterpret_cast<const uint4*>(aptr + kk + 8);
    uint4 b0 = *reinterpret_cast<const uint4*>(wptr + kk);
    uint4 b1 = *reinterpret_cast<const uint4*>(wptr + kk + 8);
    *reinterpret_cast<uint4*>(&As[srow][scol])     = a0;
    *reinterpret_cast<uint4*>(&As[srow][scol + 8]) = a1;
    *reinterpret_cast<uint4*>(&Bs[srow][scol])     = b0;
    *reinterpret_cast<uint4*>(&Bs[srow][scol + 8]) = b1;
    __syncthreads();
    int am = wave * 16 + (lane & 15);
    int kq = (lane >> 4) * 8;
#pragma unroll
    for (int ks = 0; ks < 2; ++ks) {
      bf16x8 af = *reinterpret_cast<const bf16x8*>(&As[am][kq + ks * 32]);
#pragma unroll
      for (int nb = 0; nb < 4; ++nb) {
        bf16x8 bf = *reinterpret_cast<const bf16x8*>(&Bs[nb * 16 + (lane & 15)][kq + ks * 32]);
        acc[nb] = __builtin_amdgcn_mfma_f32_16x16x32_bf16(af, bf, acc[nb], 0, 0, 0);
      }
    }
  }
  int quad = lane >> 4;
#pragma unroll
  for (int nb = 0; nb < 4; ++nb) {
    int n = n0 + nb * 16 + (lane & 15);
    float bv = bias1[n] + (bias2 ? bias2[n] : 0.0f);
    int g = n >> 9, k = n & 511;
#pragma unroll
    for (int r = 0; r < 4; ++r) {
      int m = m0 + wave * 16 + quad * 4 + r;
      int t = m >> 5, b = m & (BATCH - 1);
      out[(((long)t * BATCH + b) * HID + k) * 4 + g] = f2bf(acc[nb][r] + bv);
    }
  }
}

// 16x16x32 K=512 fragment GEMM: A rows from coherent global, B from LDS region.
// STATS: also accumulate Σx, Σx² of this lane's 128 A elements (for fused LN).
template <bool STATS>
__device__ __forceinline__ f32x4 frag_gemm(const u16* aptr, int kq,
                                           const u16 (*w)[520], int wrow,
                                           float& s, float& s2) {
  const u64* xp = reinterpret_cast<const u64*>(aptr);
  f32x4 a0 = {0.f,0.f,0.f,0.f}, a1 = {0.f,0.f,0.f,0.f};
#pragma unroll
  for (int ks = 0; ks < 16; ++ks) {
    union { u64 q[2]; unsigned d[4]; bf16x8 v; } c;
    c.q[0] = ld_dev(xp + ks * 8);
    c.q[1] = ld_dev(xp + ks * 8 + 1);
    if (STATS) {
#pragma unroll
      for (int i = 0; i < 4; ++i) {
        union { unsigned u; float f; } lo, hi;
        lo.u = c.d[i] << 16;
        hi.u = c.d[i] & 0xffff0000u;
        s  += lo.f + hi.f;
        s2 += lo.f * lo.f + hi.f * hi.f;
      }
    }
    bf16x8 bfr = *reinterpret_cast<const bf16x8*>(&w[wrow][kq + ks * 32]);
    if (ks & 1) a1 = __builtin_amdgcn_mfma_f32_16x16x32_bf16(c.v, bfr, a1, 0, 0, 0);
    else        a0 = __builtin_amdgcn_mfma_f32_16x16x32_bf16(c.v, bfr, a0, 0, 0, 0);
  }
  return a0 + a1;
}

// ---------------- persistent recurrent role (ROLE: 0=LSTM 1=GRU 2=RNN) ----------------
// GRU/RNN consume the RAW upstream ring `up` and apply LayerNorm implicitly:
// pre-scaled x-weights (g∘W) + in-wave row stats + per-column (Gn,Bn) fixup.
template <int ROLE>
__device__ void recur_role(
    int wg, const u16* __restrict__ xg, const u16* __restrict__ up,
    const u16* __restrict__ wih, const u16* __restrict__ whh,
    const float* __restrict__ bih, const float* __restrict__ bhh,
    const float* __restrict__ Gn, const float* __restrict__ Bn,
    u16* __restrict__ hist, const int* fl_up, int* fl_own, const int* cons,
    u16 (*w_lds)[520], float (*gx)[33], float (*gh)[33], u16 (*hs)[8])
{
  constexpr int NG = (ROLE == 0) ? 4 : (ROLE == 1) ? 3 : 1;
  constexpr int NPAD = (ROLE == 2) ? 16 : 32;
  constexpr int XROWS = (ROLE > 0) ? NG * 8 : 0;   // x-weight rows staged
  constexpr int TOT = XROWS + NG * 8;
  constexpr int RH = (ROLE == 2) ? 2 : RING;
  int tid = threadIdx.x, lane = tid & 63, wave = tid >> 6;
  int hbase = wg * 8;

  // stage weights compactly: rows [0,XROWS) = g∘W_ih slice, [XROWS,TOT) = W_hh slice
  for (int idx = tid; idx < TOT * 64; idx += 256) {
    int row = idx >> 6, chunk = idx & 63;
    int n = (row < XROWS) ? row : (row - XROWS);
    const u16* src = (row < XROWS) ? wih : whh;
    int g = n >> 3, dd = n & 7;
    uint4 v = *reinterpret_cast<const uint4*>(src + ((long)(g * 512 + hbase + dd)) * 512 + chunk * 8);
    *reinterpret_cast<uint4*>(&w_lds[row][chunk * 8]) = v;
  }
  __syncthreads();

  int mt = wave & 1, nt = wave >> 1;
  bool mact = (nt * 16) < NPAD;
  int colw = nt * 16 + (lane & 15);
  int wr = (colw < NG * 8) ? colw : (NG * 8 - 1);   // clamped B row (cols>=NG*8 unused)
  int arow = mt * 16 + (lane & 15);
  int kq = (lane >> 4) * 8;
  int quad = lane >> 4;
  float Gw = 0.f, bxc = 0.f, bhw = 0.f;
  if (mact && colw < NG * 8) {
    int g = colw >> 3, dd = colw & 7;
    int n = g * 512 + hbase + dd;
    if constexpr (ROLE == 1) { Gw = Gn[n]; bxc = Bn[n] + bih[n]; bhw = bhh[n]; }
    if constexpr (ROLE == 2) { Gw = Gn[n]; bxc = Bn[n] + bih[n] + bhh[n]; }
    (void)g;
  }
  int b_c = tid >> 3, d_c = tid & 7;   // cell thread owns h[b_c][hbase+d_c]
  float c_st = 0.f, h_st = 0.f;

  for (int t = 0; t < T_SEQ; ++t) {
    u64 xq = 0;
    if constexpr (ROLE == 0)
      xq = *reinterpret_cast<const u64*>(xg + (((long)t * BATCH + b_c) * HID + hbase + d_c) * 4);

    // wave0 polls all conditions; other waves park at the barrier.
    if (wave == 0) {
      while (true) {
        bool ok = true;
        if constexpr (ROLE > 0) { ok &= (ld_flag(&fl_up[lane]) >= t + 1); }
        if (t > 0)              { ok &= (ld_flag(&fl_own[lane]) >= t); }
        if (cons != nullptr && t >= RH) { ok &= (ld_flag(&cons[lane]) >= t - RH + 1); }
        if (__all(ok)) break;
        __builtin_amdgcn_s_sleep(2);
      }
      __asm__ volatile("" ::: "memory");
    }
    __syncthreads();

    if (mact) {
      float s = 0.f, s2 = 0.f, dummy = 0.f;
      f32x4 aX = {0.f,0.f,0.f,0.f}, aH = {0.f,0.f,0.f,0.f};
      if constexpr (ROLE > 0)
        aX = frag_gemm<true>(up + ((long)(t & (RING - 1)) * BATCH + arow) * HID + kq,
                             kq, w_lds, wr, s, s2);
      if (t > 0)
        aH = frag_gemm<false>(hist + ((long)((t - 1) & (RH - 1)) * BATCH + arow) * HID + kq,
                              kq, w_lds + XROWS, wr, dummy, dummy);
      if constexpr (ROLE > 0) {
        // complete row stats across the 4 column groups (lanes xor 16, 32)
        s  += __shfl_xor(s, 16);  s  += __shfl_xor(s, 32);
        s2 += __shfl_xor(s2, 16); s2 += __shfl_xor(s2, 32);
        float mu = s * (1.f / 512.f);
        float var = s2 * (1.f / 512.f) - mu * mu;
        float rs = rsqrtf(var + 1e-5f);
        float rmu = rs * mu;
#pragma unroll
        for (int r = 0; r < 4; ++r) {
          int row = mt * 16 + quad * 4 + r;
          float rr  = __shfl(rs,  quad * 4 + r);
          float rmr = __shfl(rmu, quad * 4 + r);
          gx[row][colw] = rr * aX[r] - rmr * Gw + bxc;
          gh[row][colw] = aH[r] + bhw;
        }
      } else {
#pragma unroll
        for (int r = 0; r < 4; ++r) {
          int row = mt * 16 + quad * 4 + r;
          gh[row][colw] = aH[r];
        }
      }
    }
    __syncthreads();

    float hnew;
    if constexpr (ROLE == 0) {
      float xv0 = bf2f((u16)(xq));
      float xv1 = bf2f((u16)(xq >> 16));
      float xv2 = bf2f((u16)(xq >> 32));
      float xv3 = bf2f((u16)(xq >> 48));
      float h0 = gh[b_c][0 * 8 + d_c];
      float h1 = gh[b_c][1 * 8 + d_c];
      float h2 = gh[b_c][2 * 8 + d_c];
      float h3 = gh[b_c][3 * 8 + d_c];
      float ig = sigf(xv0 + h0), fg = sigf(xv1 + h1);
      float gg = tanh_fast(xv2 + h2), og = sigf(xv3 + h3);
      c_st = fg * c_st + ig * gg;
      hnew = og * tanh_fast(c_st);
    } else if constexpr (ROLE == 1) {
      float xr_ = gx[b_c][0 * 8 + d_c], xz = gx[b_c][1 * 8 + d_c], xn = gx[b_c][2 * 8 + d_c];
      float hr  = gh[b_c][0 * 8 + d_c], hz = gh[b_c][1 * 8 + d_c], hn = gh[b_c][2 * 8 + d_c];
      float r = sigf(xr_ + hr), z = sigf(xz + hz);
      float n = tanh_fast(xn + r * hn);
      hnew = (1.f - z) * n + z * h_st;
      h_st = hnew;
    } else {
      hnew = tanh_fast(gx[b_c][d_c] + gh[b_c][d_c]);
    }
    hs[b_c][d_c] = f2bf(hnew);
    __syncthreads();

    if (wave == 0) {
      int pb = lane >> 1, half = lane & 1;
      u64 val = *reinterpret_cast<const u64*>(&hs[pb][half * 4]);
      st_dev(reinterpret_cast<u64*>(hist + ((long)(t & (RH - 1)) * BATCH + pb) * HID + hbase + half * 4), val);
      __asm__ volatile("s_waitcnt vmcnt(0)" ::: "memory");
      if (tid == 0)
        __hip_atomic_store(&fl_own[wg], t + 1, __ATOMIC_RELAXED, __HIP_MEMORY_SCOPE_AGENT);
    }
  }
}

// ---------------- fused pipeline kernel: 192 WGs ----------------
// flags: [0..63] lstm, [64..127] gru, [128..191] rnn
__global__ __launch_bounds__(256) void fused_kernel(
    const u16* __restrict__ xg, const u16* __restrict__ lstm_whh,
    const u16* __restrict__ gru_wih, const u16* __restrict__ gru_whh,
    const float* __restrict__ gru_bih, const float* __restrict__ gru_bhh,
    const float* __restrict__ G1, const float* __restrict__ B1,
    const u16* __restrict__ rnn_wih, const u16* __restrict__ rnn_whh,
    const float* __restrict__ rnn_bih, const float* __restrict__ rnn_bhh,
    const float* __restrict__ G2, const float* __restrict__ B2,
    u16* h1, u16* h2, u16* h3, int* fl)
{
  __shared__ u16 w_lds[48][520];     // 49.9 KB  (total static ~58.9 KB < 64 KB)
  __shared__ float gx[32][33];       // 4.2 KB
  __shared__ float gh[32][33];       // 4.2 KB
  __shared__ u16 hs[32][8];          // 0.5 KB
  int bid = blockIdx.x;
  if (bid < 64)
    recur_role<0>(bid, xg, nullptr, nullptr, lstm_whh, nullptr, nullptr, nullptr, nullptr,
                  h1, nullptr, fl + 0, fl + 64, w_lds, gx, gh, hs);
  else if (bid < 128)
    recur_role<1>(bid - 64, nullptr, h1, gru_wih, gru_whh, gru_bih, gru_bhh, G1, B1,
                  h2, fl + 0, fl + 64, fl + 128, w_lds, gx, gh, hs);
  else
    recur_role<2>(bid - 128, nullptr, h2, rnn_wih, rnn_whh, rnn_bih, rnn_bhh, G2, B2,
                  h3, fl + 64, fl + 128, nullptr, w_lds, gx, gh, hs);
}

// ---------------- final FC ----------------
__global__ __launch_bounds__(256) void fc_kernel(
    const u16* __restrict__ hlast, const u16* __restrict__ w,
    const float* __restrict__ bias, float* __restrict__ out)
{
  int tg = blockIdx.x * 256 + threadIdx.x;
  if (tg >= BATCH * 1000) return;
  int b = tg / 1000, o = tg % 1000;
  const u16* hp = hlast + (long)b * HID;
  const u16* wp = w + (long)o * HID;
  float acc = 0.f;
  for (int k = 0; k < HID; k += 8) {
    uint4 hu = *reinterpret_cast<const uint4*>(hp + k);
    uint4 wu = *reinterpret_cast<const uint4*>(wp + k);
    u16* hsv = reinterpret_cast<u16*>(&hu);
    u16* wsv = reinterpret_cast<u16*>(&wu);
#pragma unroll
    for (int i = 0; i < 8; ++i) acc += bf2f(hsv[i]) * bf2f(wsv[i]);
  }
  out[tg] = acc + bias[o];
}

__global__ void sentinel_kernel(float* out) { out[0] = 12345.0f; }

// ---------------- launch ----------------
extern "C" void kernel_launch(void* const* d_in, const int* in_sizes, int n_in,
                              void* d_out, int out_size, void* d_ws, size_t ws_size,
                              hipStream_t stream)
{
  (void)in_sizes; (void)n_in; (void)out_size;
  const float* x        = (const float*)d_in[0];
  const float* lstm_wih = (const float*)d_in[1];
  const float* lstm_whh = (const float*)d_in[2];
  const float* lstm_bih = (const float*)d_in[3];
  const float* lstm_bhh = (const float*)d_in[4];
  const float* ln1_g    = (const float*)d_in[5];
  const float* ln1_b    = (const float*)d_in[6];
  const float* gru_wih  = (const float*)d_in[7];
  const float* gru_whh  = (const float*)d_in[8];
  const float* gru_bih  = (const float*)d_in[9];
  const float* gru_bhh  = (const float*)d_in[10];
  const float* ln2_g    = (const float*)d_in[11];
  const float* ln2_b    = (const float*)d_in[12];
  const float* rnn_wih  = (const float*)d_in[13];
  const float* rnn_whh  = (const float*)d_in[14];
  const float* rnn_bih  = (const float*)d_in[15];
  const float* rnn_bhh  = (const float*)d_in[16];
  const float* fc_w     = (const float*)d_in[17];
  const float* fc_b     = (const float*)d_in[18];
  float* out = (float*)d_out;

  char* ws = (char*)d_ws;
  size_t off = 0;
  auto alloc = [&](size_t bytes) -> void* {
    void* p = ws + off; off += (bytes + 255) & ~(size_t)255; return p;
  };
  int* flags     = (int*)alloc(192 * sizeof(int));
  u16* xbf       = (u16*)alloc((size_t)BATCH * T_SEQ * 256 * 2);
  u16* lstm_wih_b= (u16*)alloc((size_t)2048 * 256 * 2);
  u16* lstm_whh_b= (u16*)alloc((size_t)2048 * 512 * 2);
  u16* gru_wih_b = (u16*)alloc((size_t)1536 * 512 * 2);
  u16* gru_whh_b = (u16*)alloc((size_t)1536 * 512 * 2);
  u16* rnn_wih_b = (u16*)alloc((size_t)512 * 512 * 2);
  u16* rnn_whh_b = (u16*)alloc((size_t)512 * 512 * 2);
  u16* fc_w_b    = (u16*)alloc((size_t)1000 * 512 * 2);
  float* G1      = (float*)alloc(1536 * sizeof(float));
  float* B1      = (float*)alloc(1536 * sizeof(float));
  float* G2      = (float*)alloc(512 * sizeof(float));
  float* B2      = (float*)alloc(512 * sizeof(float));
  u16* xg2       = (u16*)alloc((size_t)T_SEQ * BATCH * HID * 4 * 2);  // 128 MB
  u16* h1        = (u16*)alloc((size_t)RING * BATCH * HID * 2);       // 1 MB rings
  u16* h2        = (u16*)alloc((size_t)RING * BATCH * HID * 2);
  u16* h3        = (u16*)alloc((size_t)2 * BATCH * HID * 2);          // ping-pong

  if (off > ws_size) {
    sentinel_kernel<<<1, 1, 0, stream>>>(out);
    return;
  }

  hipMemsetAsync(flags, 0, 192 * sizeof(int), stream);

  auto cast = [&](const float* src, u16* dst, int n) {
    cast_f32_bf16<<<(n + 2047) / 2048, 256, 0, stream>>>(src, dst, n);
  };
  cast(x,        xbf,        BATCH * T_SEQ * 256);
  cast(lstm_wih, lstm_wih_b, 2048 * 256);
  cast(lstm_whh, lstm_whh_b, 2048 * 512);
  cast(gru_whh,  gru_whh_b,  1536 * 512);
  cast(rnn_whh,  rnn_whh_b,  512 * 512);
  cast(fc_w,     fc_w_b,     1000 * 512);

  // LN-folded input weights: W' = bf16(W ∘ g), Gn = Σ g*W, Bn = Σ b*W
  prep_wih<<<1536 / 4, 256, 0, stream>>>(gru_wih, ln1_g, ln1_b, gru_wih_b, G1, B1, 1536);
  prep_wih<<<512 / 4, 256, 0, stream>>>(rnn_wih, ln2_g, ln2_b, rnn_wih_b, G2, B2, 512);

  const int M64 = (BATCH * T_SEQ) / 64;  // 512
  gemm_xg<<<dim3(M64, 2048 / 64), 256, 0, stream>>>(
      xbf, lstm_wih_b, lstm_bih, lstm_bhh, xg2, 2048, 256, 1024, 1);

  fused_kernel<<<192, 256, 0, stream>>>(
      xg2, lstm_whh_b,
      gru_wih_b, gru_whh_b, gru_bih, gru_bhh, G1, B1,
      rnn_wih_b, rnn_whh_b, rnn_bih, rnn_bhh, G2, B2,
      h1, h2, h3, flags);

  // h3 last written slot = (T_SEQ-1)&1 = 1
  fc_kernel<<<(BATCH * 1000 + 255) / 256, 256, 0, stream>>>(
      h3 + (size_t)BATCH * HID, fc_w_b, fc_b, out);
}